// Round 1
// baseline (221.818 us; speedup 1.0000x reference)
//
#include <hip/hip_runtime.h>
#include <hip/hip_bf16.h>

// Problem constants
#define B_  32
#define M_  64
#define K_  36
#define DS_ 512
#define DX_ 128
#define DQ_ 512
#define H_  256

#define TM 8   // rows of s2 per block in kernel A
#define KB 9   // k's per block in kernel B (36 = 4*9)

// ---------------------------------------------------------------------------
// Kernel A: per 8-row tile of s2 (B*M = 2048 rows total):
//   pre_s[r,h] = sum_d s2[r,d] * score_w1[d,h]              (h = 0..255)
//   h1[r,h]    = relu(sum_d s2[r,d]*h_w1[d,h] + h_b1[h])
//   h_s[r,f]   = sum_h h1[r,h]*h_w2[h,f] + h_b2[f]          (f = 0..127)
// ---------------------------------------------------------------------------
__global__ __launch_bounds__(256) void kernA(
    const float* __restrict__ s2,
    const float* __restrict__ score_w1,  // (1152,256) row-major
    const float* __restrict__ h_w1,      // (512,256)
    const float* __restrict__ h_b1,      // (256)
    const float* __restrict__ h_w2,      // (256,128)
    const float* __restrict__ h_b2,      // (128)
    float* __restrict__ pre_s,           // (2048,256)
    float* __restrict__ h_s)             // (2048,128)
{
    __shared__ float sRow[TM][DS_];      // 16 KB
    __shared__ float h1[TM][H_];         // 8 KB
    const int t  = threadIdx.x;
    const int r0 = blockIdx.x * TM;

    // stage s2 tile: TM*512 = 4096 floats = 1024 float4
    {
        const float4* src = (const float4*)(s2 + (size_t)r0 * DS_);
        float4* dst = (float4*)(&sRow[0][0]);
        #pragma unroll
        for (int i = 0; i < (TM * DS_ / 4) / 256; ++i)
            dst[t + i * 256] = src[t + i * 256];
    }
    __syncthreads();

    float accS[TM], accH[TM];
    #pragma unroll
    for (int i = 0; i < TM; ++i) { accS[i] = 0.f; accH[i] = 0.f; }

    #pragma unroll 4
    for (int d = 0; d < DS_; ++d) {
        const float ws = score_w1[d * H_ + t];
        const float wh = h_w1[d * H_ + t];
        #pragma unroll
        for (int i = 0; i < TM; ++i) {
            const float sv = sRow[i][d];   // LDS broadcast
            accS[i] = fmaf(sv, ws, accS[i]);
            accH[i] = fmaf(sv, wh, accH[i]);
        }
    }

    const float b1v = h_b1[t];
    #pragma unroll
    for (int i = 0; i < TM; ++i) {
        pre_s[(size_t)(r0 + i) * H_ + t] = accS[i];
        h1[i][t] = fmaxf(accH[i] + b1v, 0.f);
    }
    __syncthreads();

    // h_s: TM*128 = 1024 outputs over 256 threads -> 4 rows per thread
    const int f    = t & 127;
    const int half = t >> 7;          // 0 or 1
    const float b2v = h_b2[f];
    #pragma unroll
    for (int i0 = 0; i0 < TM / 2; ++i0) {
        const int i = half * (TM / 2) + i0;
        float acc = b2v;
        #pragma unroll 4
        for (int h = 0; h < H_; ++h)
            acc = fmaf(h1[i][h], h_w2[h * DX_ + f], acc);
        h_s[(size_t)(r0 + i) * DX_ + f] = acc;
    }
}

// ---------------------------------------------------------------------------
// Kernel B: cvec[b,k,h] = sum_d x0[b,k,d]*w_x[d,h] + sum_d q[b,d]*w_q[d,h]
//                         + score_b1[h]
// grid = B*4 blocks, each handles 9 k's.
// ---------------------------------------------------------------------------
__global__ __launch_bounds__(256) void kernB(
    const float* __restrict__ x0,        // (B,K,128)
    const float* __restrict__ q,         // (B,512)
    const float* __restrict__ score_w1,  // (1152,256)
    const float* __restrict__ score_b1,  // (256)
    float* __restrict__ cvec)            // (B,K,256)
{
    __shared__ float qv[DQ_];            // 2 KB
    __shared__ float xv[KB * DX_];       // 4.5 KB
    const int t  = threadIdx.x;
    const int b  = blockIdx.x >> 2;
    const int kq = blockIdx.x & 3;

    qv[t]       = q[(size_t)b * DQ_ + t];
    qv[t + 256] = q[(size_t)b * DQ_ + 256 + t];
    {
        const float* xsrc = x0 + ((size_t)b * K_ + kq * KB) * DX_;
        for (int i = t; i < KB * DX_; i += 256) xv[i] = xsrc[i];
    }
    __syncthreads();

    float qacc = score_b1[t];
    #pragma unroll 4
    for (int d = 0; d < DQ_; ++d)
        qacc = fmaf(qv[d], score_w1[(DS_ + DX_ + d) * H_ + t], qacc);

    float acc[KB];
    #pragma unroll
    for (int kk = 0; kk < KB; ++kk) acc[kk] = qacc;

    #pragma unroll 2
    for (int d = 0; d < DX_; ++d) {
        const float w = score_w1[(DS_ + d) * H_ + t];
        #pragma unroll
        for (int kk = 0; kk < KB; ++kk)
            acc[kk] = fmaf(xv[kk * DX_ + d], w, acc[kk]);
    }
    #pragma unroll
    for (int kk = 0; kk < KB; ++kk)
        cvec[((size_t)b * K_ + kq * KB + kk) * H_ + t] = acc[kk];
}

// ---------------------------------------------------------------------------
// Kernel C: one block per (b,k). Logits over m, softmax over m, then
//   out[b,k,0:128]   = x0[b,k,:]
//   out[b,k,128:256] = sum_m att[m] * h_s[b,m,:]
// ---------------------------------------------------------------------------
__global__ __launch_bounds__(256) void kernC(
    const float* __restrict__ pre_s,     // (B*64,256)
    const float* __restrict__ h_s,       // (B*64,128)
    const float* __restrict__ cvec,      // (B*K,256)
    const float* __restrict__ score_w2,  // (256,1)
    const float* __restrict__ x0,        // (B*K,128)
    float* __restrict__ out)             // (B*K,256)
{
    __shared__ float cw[H_];
    __shared__ float w2s[H_];
    __shared__ float logit[M_];
    __shared__ float att[M_];
    const int t  = threadIdx.x;
    const int bk = blockIdx.x;           // 0..1151
    const int b  = bk / K_;

    cw[t]  = cvec[(size_t)bk * H_ + t];
    w2s[t] = score_w2[t];
    __syncthreads();

    const int wave = t >> 6, lane = t & 63;
    const float c0 = cw[lane],        c1 = cw[lane + 64],
                c2 = cw[lane + 128],  c3 = cw[lane + 192];
    const float v0 = w2s[lane],       v1 = w2s[lane + 64],
                v2 = w2s[lane + 128], v3 = w2s[lane + 192];

    const float* ps = pre_s + (size_t)b * M_ * H_;
    for (int mi = 0; mi < M_ / 4; ++mi) {
        const int m = wave * (M_ / 4) + mi;
        const float* p = ps + (size_t)m * H_;
        float partial = fmaxf(p[lane]       + c0, 0.f) * v0
                      + fmaxf(p[lane + 64]  + c1, 0.f) * v1
                      + fmaxf(p[lane + 128] + c2, 0.f) * v2
                      + fmaxf(p[lane + 192] + c3, 0.f) * v3;
        #pragma unroll
        for (int off = 32; off > 0; off >>= 1)
            partial += __shfl_down(partial, off, 64);
        if (lane == 0) logit[m] = partial;
    }
    __syncthreads();

    if (wave == 0) {   // softmax over m = 64 (score_b2 is constant -> cancels)
        const float L = logit[lane];
        float mx = L;
        #pragma unroll
        for (int off = 32; off > 0; off >>= 1)
            mx = fmaxf(mx, __shfl_xor(mx, off, 64));
        const float e = expf(L - mx);
        float s = e;
        #pragma unroll
        for (int off = 32; off > 0; off >>= 1)
            s += __shfl_xor(s, off, 64);
        att[lane] = e / s;
    }
    __syncthreads();

    float* o = out + (size_t)bk * (2 * DX_);
    if (t < DX_) {
        const int f = t;
        const float* hp = h_s + (size_t)b * M_ * DX_ + f;
        float acc = 0.f;
        #pragma unroll 8
        for (int m = 0; m < M_; ++m)
            acc = fmaf(att[m], hp[(size_t)m * DX_], acc);
        o[DX_ + f] = acc;
    } else {
        const int f = t - DX_;
        o[f] = x0[(size_t)bk * DX_ + f];
    }
}

extern "C" void kernel_launch(void* const* d_in, const int* in_sizes, int n_in,
                              void* d_out, int out_size, void* d_ws, size_t ws_size,
                              hipStream_t stream) {
    (void)in_sizes; (void)n_in; (void)out_size; (void)ws_size;
    const float* s2       = (const float*)d_in[0];
    const float* x0       = (const float*)d_in[1];
    const float* q        = (const float*)d_in[2];
    const float* score_w1 = (const float*)d_in[3];
    const float* score_b1 = (const float*)d_in[4];
    const float* score_w2 = (const float*)d_in[5];
    // d_in[6] = score_b2 (cancels in softmax)
    const float* h_w1     = (const float*)d_in[7];
    const float* h_b1     = (const float*)d_in[8];
    const float* h_w2     = (const float*)d_in[9];
    const float* h_b2     = (const float*)d_in[10];
    float* out = (float*)d_out;

    float* ws    = (float*)d_ws;
    float* pre_s = ws;                               // 2048*256
    float* h_s   = ws + (size_t)B_ * M_ * H_;        // 2048*128
    float* cvec  = h_s + (size_t)B_ * M_ * DX_;      // 1152*256

    kernA<<<(B_ * M_) / TM, 256, 0, stream>>>(s2, score_w1, h_w1, h_b1, h_w2,
                                              h_b2, pre_s, h_s);
    kernB<<<B_ * 4, 256, 0, stream>>>(x0, q, score_w1, score_b1, cvec);
    kernC<<<B_ * K_, 256, 0, stream>>>(pre_s, h_s, cvec, score_w2, x0, out);
}

// Round 2
// 158.018 us; speedup vs baseline: 1.4037x; 1.4037x over previous
//
#include <hip/hip_runtime.h>
#include <hip/hip_bf16.h>

// Problem constants
#define B_  32
#define M_  64
#define K_  36
#define DS_ 512
#define DX_ 128
#define DQ_ 512
#define H_  256

#define TM 8   // rows of s2 per block in kernel A

// ---------------------------------------------------------------------------
// Kernel A (grid = 544):
//  blocks 0..511: tile = bid>>1 (8 rows of s2), half = bid&1.
//    half==0: pre_s[r,h] = sum_d s2[r,d]*score_w1[d,h]
//    half==1: h1 = relu(s2 . h_w1 + h_b1);  h_s = h1 . h_w2 + h_b2
//  blocks 512..543: qpre[b,h] = sum_d q[b,d]*w_q[d,h] + score_b1[h]
// ---------------------------------------------------------------------------
__global__ __launch_bounds__(256) void kernA(
    const float* __restrict__ s2,
    const float* __restrict__ score_w1,  // (1152,256) row-major
    const float* __restrict__ h_w1,      // (512,256)
    const float* __restrict__ h_b1,      // (256)
    const float* __restrict__ h_w2,      // (256,128)
    const float* __restrict__ h_b2,      // (128)
    const float* __restrict__ q,         // (B,512)
    const float* __restrict__ score_b1,  // (256)
    float* __restrict__ pre_s,           // (2048,256)
    float* __restrict__ h_s,             // (2048,128)
    float* __restrict__ qpre)            // (B,256)
{
    __shared__ float sRow[TM][DS_];      // 16 KB (aliased as qv for q-blocks)
    __shared__ float h1s[TM][H_];        // 8 KB
    const int t   = threadIdx.x;
    const int bid = blockIdx.x;

    if (bid >= 512) {                    // ---- qpre blocks ----
        float* qv = &sRow[0][0];
        const int b = bid - 512;
        qv[t]       = q[(size_t)b * DQ_ + t];
        qv[t + 256] = q[(size_t)b * DQ_ + 256 + t];
        __syncthreads();
        float acc = score_b1[t];
        const float* wq = score_w1 + (size_t)(DS_ + DX_) * H_ + t;
        #pragma unroll 8
        for (int d = 0; d < DQ_; ++d)
            acc = fmaf(qv[d], wq[(size_t)d * H_], acc);
        qpre[(size_t)b * H_ + t] = acc;
        return;
    }

    const int half = bid & 1;
    const int r0   = (bid >> 1) * TM;

    // stage s2 tile: 8*512 floats = 1024 float4
    {
        const float4* src = (const float4*)(s2 + (size_t)r0 * DS_);
        float4* dst = (float4*)(&sRow[0][0]);
        #pragma unroll
        for (int i = 0; i < 4; ++i)
            dst[t + i * 256] = src[t + i * 256];
    }
    __syncthreads();

    const float* w = (half ? h_w1 : score_w1) + t;
    float acc[TM];
    #pragma unroll
    for (int i = 0; i < TM; ++i) acc[i] = 0.f;

    #pragma unroll 2
    for (int d4 = 0; d4 < DS_; d4 += 4) {
        const float w0 = w[(size_t)(d4 + 0) * H_];
        const float w1 = w[(size_t)(d4 + 1) * H_];
        const float w2v = w[(size_t)(d4 + 2) * H_];
        const float w3 = w[(size_t)(d4 + 3) * H_];
        #pragma unroll
        for (int i = 0; i < TM; ++i) {
            const float4 s4 = *(const float4*)&sRow[i][d4];
            acc[i] = fmaf(s4.x, w0, acc[i]);
            acc[i] = fmaf(s4.y, w1, acc[i]);
            acc[i] = fmaf(s4.z, w2v, acc[i]);
            acc[i] = fmaf(s4.w, w3, acc[i]);
        }
    }

    if (!half) {
        #pragma unroll
        for (int i = 0; i < TM; ++i)
            pre_s[(size_t)(r0 + i) * H_ + t] = acc[i];
        return;
    }

    const float b1v = h_b1[t];
    #pragma unroll
    for (int i = 0; i < TM; ++i)
        h1s[i][t] = fmaxf(acc[i] + b1v, 0.f);
    __syncthreads();

    // h_s: 8 rows x 128 cols over 256 threads -> 4 rows per thread
    const int f  = t & 127;
    const int hh = t >> 7;               // 0 or 1
    const float b2v = h_b2[f];
    const float* w2p = h_w2 + f;
    #pragma unroll
    for (int i0 = 0; i0 < TM / 2; ++i0) {
        const int i = hh * (TM / 2) + i0;
        float a = b2v;
        #pragma unroll 4
        for (int h = 0; h < H_; ++h)
            a = fmaf(h1s[i][h], w2p[(size_t)h * DX_], a);
        h_s[(size_t)(r0 + i) * DX_ + f] = a;
    }
}

// ---------------------------------------------------------------------------
// Kernel C: one block per (b,k).
//   cw[h]  = qpre[b,h] + sum_d x0[b,k,d]*w_x[d,h]
//   logit[m] = sum_h relu(pre_s[b,m,h] + cw[h]) * w2[h]
//   att = softmax_m(logit);  out[b,k, 0:128] = x0[b,k,:]
//   out[b,k,128:256] = sum_m att[m] * h_s[b,m,:]
// ---------------------------------------------------------------------------
__global__ __launch_bounds__(256) void kernC(
    const float* __restrict__ pre_s,     // (B*64,256)
    const float* __restrict__ h_s,       // (B*64,128)
    const float* __restrict__ qpre,      // (B,256)
    const float* __restrict__ score_w1,  // (1152,256)
    const float* __restrict__ score_w2,  // (256,1)
    const float* __restrict__ x0,        // (B*K,128)
    float* __restrict__ out)             // (B*K,256)
{
    __shared__ float xv[DX_];
    __shared__ float cw[H_];
    __shared__ float w2s[H_];
    __shared__ float logit[M_];
    __shared__ float att[M_];
    const int t  = threadIdx.x;
    const int bk = blockIdx.x;           // 0..1151
    const int b  = bk / K_;

    if (t < DX_) xv[t] = x0[(size_t)bk * DX_ + t];
    w2s[t] = score_w2[t];
    __syncthreads();

    // cw = qpre[b] + x0[b,k] . w_x
    {
        float cacc = qpre[(size_t)b * H_ + t];
        const float* wx = score_w1 + (size_t)DS_ * H_ + t;
        #pragma unroll 4
        for (int d = 0; d < DX_; ++d)
            cacc = fmaf(xv[d], wx[(size_t)d * H_], cacc);
        cw[t] = cacc;
    }
    __syncthreads();

    const int wave = t >> 6, lane = t & 63;
    const float c0 = cw[lane],        c1 = cw[lane + 64],
                c2 = cw[lane + 128],  c3 = cw[lane + 192];
    const float v0 = w2s[lane],       v1 = w2s[lane + 64],
                v2 = w2s[lane + 128], v3 = w2s[lane + 192];

    const float* ps = pre_s + (size_t)b * M_ * H_;
    for (int mi = 0; mi < M_ / 4; ++mi) {
        const int m = wave * (M_ / 4) + mi;
        const float* p = ps + (size_t)m * H_;
        float partial = fmaxf(p[lane]       + c0, 0.f) * v0
                      + fmaxf(p[lane + 64]  + c1, 0.f) * v1
                      + fmaxf(p[lane + 128] + c2, 0.f) * v2
                      + fmaxf(p[lane + 192] + c3, 0.f) * v3;
        #pragma unroll
        for (int off = 32; off > 0; off >>= 1)
            partial += __shfl_down(partial, off, 64);
        if (lane == 0) logit[m] = partial;
    }
    __syncthreads();

    if (wave == 0) {   // softmax over m = 64 (score_b2 is constant -> cancels)
        const float L = logit[lane];
        float mx = L;
        #pragma unroll
        for (int off = 32; off > 0; off >>= 1)
            mx = fmaxf(mx, __shfl_xor(mx, off, 64));
        const float e = expf(L - mx);
        float s = e;
        #pragma unroll
        for (int off = 32; off > 0; off >>= 1)
            s += __shfl_xor(s, off, 64);
        att[lane] = e / s;
    }
    __syncthreads();

    float* o = out + (size_t)bk * (2 * DX_);
    if (t < DX_) {
        const int f = t;
        const float* hp = h_s + (size_t)b * M_ * DX_ + f;
        float acc = 0.f;
        #pragma unroll 8
        for (int m = 0; m < M_; ++m)
            acc = fmaf(att[m], hp[(size_t)m * DX_], acc);
        o[DX_ + f] = acc;
    } else {
        o[t - DX_] = xv[t - DX_];
    }
}

extern "C" void kernel_launch(void* const* d_in, const int* in_sizes, int n_in,
                              void* d_out, int out_size, void* d_ws, size_t ws_size,
                              hipStream_t stream) {
    (void)in_sizes; (void)n_in; (void)out_size; (void)ws_size;
    const float* s2       = (const float*)d_in[0];
    const float* x0       = (const float*)d_in[1];
    const float* q        = (const float*)d_in[2];
    const float* score_w1 = (const float*)d_in[3];
    const float* score_b1 = (const float*)d_in[4];
    const float* score_w2 = (const float*)d_in[5];
    // d_in[6] = score_b2 (cancels in softmax)
    const float* h_w1     = (const float*)d_in[7];
    const float* h_b1     = (const float*)d_in[8];
    const float* h_w2     = (const float*)d_in[9];
    const float* h_b2     = (const float*)d_in[10];
    float* out = (float*)d_out;

    float* ws    = (float*)d_ws;
    float* pre_s = ws;                               // 2048*256
    float* h_s   = ws + (size_t)B_ * M_ * H_;        // 2048*128
    float* qpre  = h_s + (size_t)B_ * M_ * DX_;      // 32*256

    kernA<<<544, 256, 0, stream>>>(s2, score_w1, h_w1, h_b1, h_w2, h_b2,
                                   q, score_b1, pre_s, h_s, qpre);
    kernC<<<B_ * K_, 256, 0, stream>>>(pre_s, h_s, qpre, score_w1, score_w2,
                                       x0, out);
}

// Round 3
// 131.131 us; speedup vs baseline: 1.6916x; 1.2050x over previous
//
#include <hip/hip_runtime.h>

// Problem constants
#define B_  32
#define M_  64
#define K_  36
#define DS_ 512
#define DX_ 128
#define DQ_ 512
#define H_  256

#define TMA  16     // rows of s2 per GEMM block in kernA
#define DCH  128    // d-chunk (split-K factor 4)

// ---------------------------------------------------------------------------
// Kernel A (grid = 1056, no LDS):
//  blocks 0..1023: tile = bid>>3 (16 rows), mat = bid&1, dq = (bid>>1)&3.
//    atomicAdd partial GEMM: (mat?ph1:pre_s)[r,h] += sum_{d in chunk} s2[r,d]*W[d,h]
//    s2 accessed with block-uniform indices -> scalar (s_load) path.
//  blocks 1024..1055: qpre[b,h] = sum_d q[b,d]*w_q[d,h] + score_b1[h]
// ---------------------------------------------------------------------------
__global__ __launch_bounds__(256) void kernA(
    const float* __restrict__ s2,        // (2048,512)
    const float* __restrict__ score_w1,  // (1152,256)
    const float* __restrict__ h_w1,      // (512,256)
    const float* __restrict__ q,         // (B,512)
    const float* __restrict__ score_b1,  // (256)
    float* __restrict__ pre_s,           // (2048,256)  zero-init
    float* __restrict__ ph1,             // (2048,256)  zero-init
    float* __restrict__ qpre)            // (B,256)
{
    const int t   = threadIdx.x;
    const int bid = blockIdx.x;

    if (bid >= 1024) {                   // ---- qpre blocks ----
        const int b = bid - 1024;
        const float* qp = q + (size_t)b * DQ_;          // block-uniform
        const float* wq = score_w1 + (size_t)(DS_ + DX_) * H_ + t;
        float a0 = score_b1[t], a1 = 0.f, a2 = 0.f, a3 = 0.f;
        for (int d = 0; d < DQ_; d += 4) {
            const float4 q4 = *(const float4*)(qp + d);  // scalar load
            a0 = fmaf(q4.x, wq[(size_t)(d + 0) * H_], a0);
            a1 = fmaf(q4.y, wq[(size_t)(d + 1) * H_], a1);
            a2 = fmaf(q4.z, wq[(size_t)(d + 2) * H_], a2);
            a3 = fmaf(q4.w, wq[(size_t)(d + 3) * H_], a3);
        }
        qpre[(size_t)b * H_ + t] = (a0 + a1) + (a2 + a3);
        return;
    }

    const int tile = bid >> 3;
    const int mat  = bid & 1;
    const int dq   = (bid >> 1) & 3;

    const float* w  = (mat ? h_w1 : score_w1) + (size_t)(dq * DCH) * H_ + t;
    const float* sp = s2 + (size_t)tile * TMA * DS_ + dq * DCH;  // block-uniform

    float acc[TMA];
    #pragma unroll
    for (int i = 0; i < TMA; ++i) acc[i] = 0.f;

    for (int d = 0; d < DCH; d += 4) {
        const float w0 = w[(size_t)(d + 0) * H_];
        const float w1 = w[(size_t)(d + 1) * H_];
        const float w2v = w[(size_t)(d + 2) * H_];
        const float w3 = w[(size_t)(d + 3) * H_];
        #pragma unroll
        for (int i = 0; i < TMA; ++i) {
            const float4 s4 = *(const float4*)(sp + (size_t)i * DS_ + d); // s_load_dwordx4
            acc[i] = fmaf(s4.x, w0, acc[i]);
            acc[i] = fmaf(s4.y, w1, acc[i]);
            acc[i] = fmaf(s4.z, w2v, acc[i]);
            acc[i] = fmaf(s4.w, w3, acc[i]);
        }
    }

    float* dst = (mat ? ph1 : pre_s) + (size_t)tile * TMA * H_ + t;
    #pragma unroll
    for (int i = 0; i < TMA; ++i)
        atomicAdd(dst + (size_t)i * H_, acc[i]);
}

// ---------------------------------------------------------------------------
// Kernel C: one block per (b,k).
//   cw[h]    = qpre[b,h] + sum_d x0[b,k,d]*w_x[d,h]
//   logit[m] = sum_h relu(pre_s[b,m,h] + cw[h]) * w2[h]
//   att      = softmax_m(logit)
//   ragg[h]  = sum_m att[m] * relu(ph1[b,m,h] + h_b1[h])
//   out[b,k,128:256] = ragg . h_w2 + h_b2 ;  out[b,k,0:128] = x0[b,k,:]
// ---------------------------------------------------------------------------
__global__ __launch_bounds__(256) void kernC(
    const float* __restrict__ pre_s,     // (2048,256)
    const float* __restrict__ ph1,       // (2048,256)
    const float* __restrict__ qpre,      // (B,256)
    const float* __restrict__ score_w1,  // (1152,256)
    const float* __restrict__ score_w2,  // (256,1)
    const float* __restrict__ h_b1,      // (256)
    const float* __restrict__ h_w2,      // (256,128)
    const float* __restrict__ h_b2,      // (128)
    const float* __restrict__ x0,        // (B*K,128)
    float* __restrict__ out)             // (B*K,256)
{
    __shared__ float cw[H_];             // reused later as ragg
    __shared__ float w2s[H_];
    __shared__ float logit[M_];
    __shared__ float att[M_];
    __shared__ float part[DX_];

    const int t  = threadIdx.x;
    const int bk = blockIdx.x;           // 0..1151
    const int b  = bk / K_;
    const float* x0p = x0 + (size_t)bk * DX_;   // block-uniform base

    w2s[t] = score_w2[t];
    // cw = qpre[b] + x0[b,k] . w_x   (x0 via scalar loads, 4-way ILP)
    {
        const float* wx = score_w1 + (size_t)DS_ * H_ + t;
        float a0 = qpre[(size_t)b * H_ + t], a1 = 0.f, a2 = 0.f, a3 = 0.f;
        for (int d = 0; d < DX_; d += 4) {
            const float4 x4 = *(const float4*)(x0p + d);   // scalar load
            a0 = fmaf(x4.x, wx[(size_t)(d + 0) * H_], a0);
            a1 = fmaf(x4.y, wx[(size_t)(d + 1) * H_], a1);
            a2 = fmaf(x4.z, wx[(size_t)(d + 2) * H_], a2);
            a3 = fmaf(x4.w, wx[(size_t)(d + 3) * H_], a3);
        }
        cw[t] = (a0 + a1) + (a2 + a3);
    }
    __syncthreads();

    const int wave = t >> 6, lane = t & 63;
    const float c0 = cw[lane],        c1 = cw[lane + 64],
                c2 = cw[lane + 128],  c3 = cw[lane + 192];
    const float v0 = w2s[lane],       v1 = w2s[lane + 64],
                v2 = w2s[lane + 128], v3 = w2s[lane + 192];

    const float* ps = pre_s + (size_t)b * M_ * H_;
    #pragma unroll 2
    for (int mi = 0; mi < M_ / 4 / 2; ++mi) {   // 2 m's per iter, 16 per wave
        const int m0 = wave * (M_ / 4) + mi * 2;
        const float* p0 = ps + (size_t)m0 * H_;
        const float* p1 = p0 + H_;
        float pa = fmaxf(p0[lane]       + c0, 0.f) * v0
                 + fmaxf(p0[lane + 64]  + c1, 0.f) * v1
                 + fmaxf(p0[lane + 128] + c2, 0.f) * v2
                 + fmaxf(p0[lane + 192] + c3, 0.f) * v3;
        float pb = fmaxf(p1[lane]       + c0, 0.f) * v0
                 + fmaxf(p1[lane + 64]  + c1, 0.f) * v1
                 + fmaxf(p1[lane + 128] + c2, 0.f) * v2
                 + fmaxf(p1[lane + 192] + c3, 0.f) * v3;
        #pragma unroll
        for (int off = 32; off > 0; off >>= 1) {
            pa += __shfl_down(pa, off, 64);
            pb += __shfl_down(pb, off, 64);
        }
        if (lane == 0) { logit[m0] = pa; logit[m0 + 1] = pb; }
    }
    __syncthreads();

    if (wave == 0) {   // softmax over m = 64 (score_b2 cancels)
        const float L = logit[lane];
        float mx = L;
        #pragma unroll
        for (int off = 32; off > 0; off >>= 1)
            mx = fmaxf(mx, __shfl_xor(mx, off, 64));
        const float e = expf(L - mx);
        float s = e;
        #pragma unroll
        for (int off = 32; off > 0; off >>= 1)
            s += __shfl_xor(s, off, 64);
        att[lane] = e / s;
    }
    __syncthreads();

    // ragg[h=t] = sum_m att[m] * relu(ph1[b,m,t] + h_b1[t])   (coalesced)
    {
        const float* hp = ph1 + (size_t)b * M_ * H_ + t;
        const float b1v = h_b1[t];
        float r0 = 0.f, r1 = 0.f;
        #pragma unroll 4
        for (int m = 0; m < M_; m += 2) {
            r0 = fmaf(att[m],     fmaxf(hp[(size_t)m * H_] + b1v, 0.f), r0);
            r1 = fmaf(att[m + 1], fmaxf(hp[(size_t)(m + 1) * H_] + b1v, 0.f), r1);
        }
        cw[t] = r0 + r1;               // cw now holds ragg
    }
    __syncthreads();

    // out[128:256] = ragg . h_w2 + h_b2, split-K across thread halves
    const int f  = t & 127;
    const int hh = t >> 7;             // 0 or 1 -> h-range [hh*128, hh*128+128)
    const float* wp = h_w2 + (size_t)(hh * 128) * DX_ + f;
    float a0 = 0.f, a1 = 0.f, a2 = 0.f, a3 = 0.f;
    for (int h = 0; h < 128; h += 4) {
        a0 = fmaf(cw[hh * 128 + h + 0], wp[(size_t)(h + 0) * DX_], a0);
        a1 = fmaf(cw[hh * 128 + h + 1], wp[(size_t)(h + 1) * DX_], a1);
        a2 = fmaf(cw[hh * 128 + h + 2], wp[(size_t)(h + 2) * DX_], a2);
        a3 = fmaf(cw[hh * 128 + h + 3], wp[(size_t)(h + 3) * DX_], a3);
    }
    const float sum = (a0 + a1) + (a2 + a3);
    if (hh) part[f] = sum;
    __syncthreads();

    float* o = out + (size_t)bk * (2 * DX_);
    if (!hh) {
        o[DX_ + f] = sum + part[f] + h_b2[f];
    } else {
        o[f] = x0p[f];                 // per-lane coalesced passthrough
    }
}

extern "C" void kernel_launch(void* const* d_in, const int* in_sizes, int n_in,
                              void* d_out, int out_size, void* d_ws, size_t ws_size,
                              hipStream_t stream) {
    (void)in_sizes; (void)n_in; (void)out_size; (void)ws_size;
    const float* s2       = (const float*)d_in[0];
    const float* x0       = (const float*)d_in[1];
    const float* q        = (const float*)d_in[2];
    const float* score_w1 = (const float*)d_in[3];
    const float* score_b1 = (const float*)d_in[4];
    const float* score_w2 = (const float*)d_in[5];
    // d_in[6] = score_b2 (cancels in softmax)
    const float* h_w1     = (const float*)d_in[7];
    // d_in[8] = h_b1 (applied in kernC)
    const float* h_b1     = (const float*)d_in[8];
    const float* h_w2     = (const float*)d_in[9];
    const float* h_b2     = (const float*)d_in[10];
    float* out = (float*)d_out;

    float* ws    = (float*)d_ws;
    float* pre_s = ws;                                 // 2048*256
    float* ph1   = ws + (size_t)B_ * M_ * H_;          // 2048*256
    float* qpre  = ph1 + (size_t)B_ * M_ * H_;         // 32*256

    // zero the atomic accumulation buffers (pre_s + ph1 = 4 MB)
    hipMemsetAsync(d_ws, 0, (size_t)2 * B_ * M_ * H_ * sizeof(float), stream);

    kernA<<<1056, 256, 0, stream>>>(s2, score_w1, h_w1, q, score_b1,
                                    pre_s, ph1, qpre);
    kernC<<<B_ * K_, 256, 0, stream>>>(pre_s, ph1, qpre, score_w1, score_w2,
                                       h_b1, h_w2, h_b2, x0, out);
}